// Round 6
// baseline (152.487 us; speedup 1.0000x reference)
//
#include <hip/hip_runtime.h>

#define N_SP 16384
#define C_DIM 128
#define K_DIM 32
#define NBX   32     // blocks along n
#define TILEN 128    // n per tile
#define TILES 4      // tiles per block; NBX*TILES*TILEN == N_SP

typedef short short8 __attribute__((ext_vector_type(8)));
typedef float f32x16 __attribute__((ext_vector_type(16)));

__device__ __forceinline__ unsigned f2bfu(float f){
    return (__float_as_uint(f) + 0x8000u) >> 16;   // cheap RN to bf16 bits
}
__device__ __forceinline__ unsigned short f2bf(float f){
    return (unsigned short)f2bfu(f);
}

// swizzled index into a [row][128] ushort tile: XOR n-bits 3..6 with row&15
// -> 16B groups stay contiguous (b128 legal); rows 8 apart use disjoint banks
#define SWZ(row, n) (((row) << 7) + ((n) ^ (((row) & 15) << 3)))

union FragU { int i[4]; short8 s; };

// build one S-MFMA B-fragment (8 c-elems for column `col`) from xs row-reads
// (lane sweep over columns of one c-row = contiguous 64B -> conflict-free)
#define S_GROUP(KS, G, SACC) do {                                          \
    const int col_ = 32*(G) + l31;                                         \
    FragU f_;                                                              \
    _Pragma("unroll")                                                      \
    for (int d_ = 0; d_ < 4; ++d_){                                        \
        const int c0_ = (KS)*16 + hi*8 + 2*d_;                             \
        const unsigned lo_  = xs[SWZ(c0_,     col_)];                      \
        const unsigned h16_ = xs[SWZ(c0_ + 1, col_)];                      \
        f_.i[d_] = (int)(lo_ | (h16_ << 16));                              \
    }                                                                      \
    SACC = __builtin_amdgcn_mfma_f32_32x32x16_bf16(cwA[(KS)], f_.s, SACC, 0,0,0); \
} while (0)

#define SMAX_GROUP(G, SACC) do {                                           \
    const int col_ = 32*(G) + l31;                                         \
    const int sg_  = 16*(G) + (l31 >> 1);                                  \
    const float xa_ = __shfl(x2a, sg_);                                    \
    const float xb_ = __shfl(x2b, sg_);                                    \
    const float x2g_ = (l31 & 1) ? xb_ : xa_;                              \
    float arg_[16]; float ml_ = -3.4e38f;                                  \
    _Pragma("unroll")                                                      \
    for (int q_ = 0; q_ < 16; ++q_){                                       \
        arg_[q_] = fmaf(csx[q_], x2g_, SACC[q_] + csy[q_]);                \
        ml_ = fmaxf(ml_, arg_[q_]);                                        \
    }                                                                      \
    const float mm_ = fmaxf(ml_, __shfl_xor(ml_, 32));                     \
    float sum_ = 0.f;                                                      \
    _Pragma("unroll")                                                      \
    for (int q_ = 0; q_ < 16; ++q_){                                       \
        float p_ = __expf(arg_[q_] - mm_); arg_[q_] = p_; sum_ += p_;      \
    }                                                                      \
    sum_ += __shfl_xor(sum_, 32);                                          \
    const float r_ = 1.f / sum_;                                           \
    _Pragma("unroll")                                                      \
    for (int q_ = 0; q_ < 16; ++q_){                                       \
        const int row_ = (q_ & 3) + 8 * (q_ >> 2) + 4 * hi;                \
        aws[SWZ(row_, col_)] = f2bf(arg_[q_] * r_);                        \
    }                                                                      \
} while (0)

__global__ __launch_bounds__(64, 1) void enc_main(
    const float* __restrict__ x,              // [B][C][N]
    const unsigned short* __restrict__ cwt2b, // [K][C] bf16 of -2*scale[k]*cw[k][c]
    const float* __restrict__ combo,          // [K][2] = {scale[k], scale[k]*||cw_k||^2}
    float* __restrict__ wxacc,                // [B][K][C] (zeroed)
    float* __restrict__ wsacc)                // [B][K]    (zeroed)
{
    __shared__ unsigned short xs[C_DIM * TILEN];   // bf16 x[c][n'] swizzled (32 KB)
    __shared__ unsigned short aws[K_DIM * TILEN];  // bf16 aw[k][n'] swizzled (8 KB)

    const int t   = threadIdx.x;   // 0..63, ONE wave; thread owns cols n0+2t, n0+2t+1
    const int b   = blockIdx.y;
    const int hi  = t >> 5;
    const int l31 = t & 31;

    const float* xb = x + (size_t)b * C_DIM * N_SP;

    // held codeword A-fragments: lane l31 = k-row, hi picks 8-c half of each 16-chunk
    short8 cwA[8];
#pragma unroll
    for (int ksg = 0; ksg < 8; ++ksg)
        cwA[ksg] = *(const short8*)(const void*)(cwt2b + l31 * C_DIM + ksg * 16 + hi * 8);

    f32x16 acc0, acc1, acc2, acc3, accS;
#pragma unroll
    for (int i = 0; i < 16; ++i){
        acc0[i]=0.f; acc1[i]=0.f; acc2[i]=0.f; acc3[i]=0.f; accS[i]=0.f;
    }
    short8 ones;
#pragma unroll
    for (int i = 0; i < 8; ++i) ones[i] = (short)0x3F80;  // bf16 1.0

    for (int tile = 0; tile < TILES; ++tile){
        const int n0 = blockIdx.x * (TILES * TILEN) + tile * TILEN;
        const float2* xq = (const float2*)(xb + n0) + t;  // 512B contiguous per instr

        // ---- phase 1: stream x (float2, depth-2 x 8-wide), fp32 x2, stage bf16 ----
        float x2a = 0.f, x2b = 0.f;
        float2 cur[8], nx1[8];
#pragma unroll
        for (int j = 0; j < 8; ++j) cur[j] = xq[j * (N_SP/2)];
#pragma unroll
        for (int j = 0; j < 8; ++j) nx1[j] = xq[(8 + j) * (N_SP/2)];

#pragma unroll 1
        for (int g = 0; g < 14; ++g){
            float2 nx2[8];
#pragma unroll
            for (int j = 0; j < 8; ++j) nx2[j] = xq[((g + 2) * 8 + j) * (N_SP/2)];
#pragma unroll
            for (int j = 0; j < 8; ++j){
                const int c = g * 8 + j;
                const float a0 = cur[j].x, a1 = cur[j].y;
                x2a = fmaf(a0, a0, x2a);
                x2b = fmaf(a1, a1, x2b);
                *(unsigned*)&xs[SWZ(c, 2 * t)] = f2bfu(a0) | (f2bfu(a1) << 16);
            }
#pragma unroll
            for (int j = 0; j < 8; ++j){ cur[j] = nx1[j]; nx1[j] = nx2[j]; }
        }
#pragma unroll
        for (int gg = 14; gg < 16; ++gg){
#pragma unroll
            for (int j = 0; j < 8; ++j){
                const int c = gg * 8 + j;
                const float a0 = cur[j].x, a1 = cur[j].y;
                x2a = fmaf(a0, a0, x2a);
                x2b = fmaf(a1, a1, x2b);
                *(unsigned*)&xs[SWZ(c, 2 * t)] = f2bfu(a0) | (f2bfu(a1) << 16);
            }
#pragma unroll
            for (int j = 0; j < 8; ++j) cur[j] = nx1[j];
        }

        // ---- phase S: S[k][n] = cwt2 * x via MFMA, B-frags from xs row-reads ----
        f32x16 sA, sB, sC, sD;
#pragma unroll
        for (int i = 0; i < 16; ++i){ sA[i]=0.f; sB[i]=0.f; sC[i]=0.f; sD[i]=0.f; }

#pragma unroll
        for (int ks = 0; ks < 8; ++ks){
            S_GROUP(ks, 0, sA);
            S_GROUP(ks, 1, sB);
            S_GROUP(ks, 2, sC);
            S_GROUP(ks, 3, sD);
        }

        // ---- phase 2: softmax over k on the MFMA D-layout (4 col-groups) ----
        float csx[16], csy[16];
#pragma unroll
        for (int q = 0; q < 16; ++q){
            const int row = (q & 3) + 8 * (q >> 2) + 4 * hi;
            csx[q] = combo[2 * row];
            csy[q] = combo[2 * row + 1];
        }
        SMAX_GROUP(0, sA);
        SMAX_GROUP(1, sB);
        SMAX_GROUP(2, sC);
        SMAX_GROUP(3, sD);

        // ---- phase D: wx[k][c] += aw[k][n] * x[n][c] via MFMA (acc across tiles) ----
#pragma unroll
        for (int ks = 0; ks < 8; ++ks){            // n = 128 -> 8 k-steps of 16
            const int n8 = ks * 16 + hi * 8;
            short8 af  = *(const short8*)(const void*)&aws[SWZ(l31, n8)];
            short8 bf0 = *(const short8*)(const void*)&xs[SWZ(l31,      n8)];
            short8 bf1 = *(const short8*)(const void*)&xs[SWZ(32 + l31, n8)];
            short8 bf2 = *(const short8*)(const void*)&xs[SWZ(64 + l31, n8)];
            short8 bf3 = *(const short8*)(const void*)&xs[SWZ(96 + l31, n8)];
            acc0 = __builtin_amdgcn_mfma_f32_32x32x16_bf16(af, bf0, acc0, 0, 0, 0);
            acc1 = __builtin_amdgcn_mfma_f32_32x32x16_bf16(af, bf1, acc1, 0, 0, 0);
            acc2 = __builtin_amdgcn_mfma_f32_32x32x16_bf16(af, bf2, acc2, 0, 0, 0);
            acc3 = __builtin_amdgcn_mfma_f32_32x32x16_bf16(af, bf3, acc3, 0, 0, 0);
            accS = __builtin_amdgcn_mfma_f32_32x32x16_bf16(af, ones, accS, 0, 0, 0);
        }
    }

    // ---- epilogue: atomic-reduce block partials to global ----
    float* wxb = wxacc + (size_t)b * K_DIM * C_DIM;
#pragma unroll
    for (int rg = 0; rg < 16; ++rg){
        const int row = (rg & 3) + 8 * (rg >> 2) + 4 * hi;  // verified D layout
        atomicAdd(&wxb[row * C_DIM +      l31], acc0[rg]);
        atomicAdd(&wxb[row * C_DIM + 32 + l31], acc1[rg]);
        atomicAdd(&wxb[row * C_DIM + 64 + l31], acc2[rg]);
        atomicAdd(&wxb[row * C_DIM + 96 + l31], acc3[rg]);
    }
    if (l31 == 0){
#pragma unroll
        for (int rg = 0; rg < 16; ++rg){
            const int row = (rg & 3) + 8 * (rg >> 2) + 4 * hi;
            atomicAdd(&wsacc[b * K_DIM + row], accS[rg]);
        }
    }
}

__global__ void enc_zero(float* __restrict__ p, int n){
    const int i = blockIdx.x * 256 + threadIdx.x;
    if (i < n) p[i] = 0.f;
}

__global__ void enc_prep(const float* __restrict__ cw, const float* __restrict__ scale,
                         unsigned short* __restrict__ cwt2b, float* __restrict__ combo){
    const int t = threadIdx.x;  // 128 threads; t = c
    for (int k = 0; k < K_DIM; ++k)
        cwt2b[k * C_DIM + t] = f2bf(-2.f * scale[k] * cw[k * C_DIM + t]);
    if (t < K_DIM){
        float s = 0.f;
        for (int c = 0; c < C_DIM; ++c){
            float v = cw[t * C_DIM + c];
            s = fmaf(v, v, s);
        }
        combo[2 * t]     = scale[t];
        combo[2 * t + 1] = scale[t] * s;
    }
}

__global__ void enc_final(const float* __restrict__ wxacc, const float* __restrict__ wsacc,
                          const float* __restrict__ cw, float* __restrict__ out){
    const int i  = blockIdx.x * 256 + threadIdx.x;  // B*K*C = 131072
    const int c  = i & (C_DIM - 1);
    const int kk = (i >> 7) & (K_DIM - 1);
    const int bk = i >> 7;
    out[i] = wxacc[i] - wsacc[bk] * cw[kk * C_DIM + c];
}

extern "C" void kernel_launch(void* const* d_in, const int* in_sizes, int n_in,
                              void* d_out, int out_size, void* d_ws, size_t ws_size,
                              hipStream_t stream){
    (void)in_sizes; (void)n_in; (void)out_size; (void)ws_size;
    const float* x     = (const float*)d_in[0];
    const float* cw    = (const float*)d_in[1];
    const float* scale = (const float*)d_in[2];
    float* out = (float*)d_out;

    float* wxacc = (float*)d_ws;                            // 131072 f32
    float* wsacc = wxacc + 32 * 32 * C_DIM;                 // 1024 f32
    float* combo = wsacc + 32 * 32;                         // 64 f32
    unsigned short* cwt2b = (unsigned short*)(combo + 64);  // 4096 ushort

    const int nz = 32 * 32 * C_DIM + 32 * 32;
    enc_zero<<<(nz + 255) / 256, 256, 0, stream>>>(wxacc, nz);
    enc_prep<<<1, 128, 0, stream>>>(cw, scale, cwt2b, combo);
    enc_main<<<dim3(NBX, 32), 64, 0, stream>>>(x, cwt2b, combo, wxacc, wsacc);
    enc_final<<<512, 256, 0, stream>>>(wxacc, wsacc, cw, out);
}